// Round 13
// baseline (134.912 us; speedup 1.0000x reference)
//
#include <hip/hip_runtime.h>

// B=4096, F0=39, D=16, L=(128,128), H1=64
// Round-13: batch-major M. mfma_f32_32x32x16_f16 with M = 32 BATCHES, one d-pair
// per wave; N=128 m-channels; K=(i,j) identical to r12 (folded L0 30 + L1 80 = 110).
//  - Lane's A row = x[b=lane&31, :, d]: 40 halfs in 20 h2 REGISTERS (xw), loaded once.
//    A-frag = splat(xi) * window(xw): xi via i=2*(ig*2+kh)+half -> reg (ig*2+kh),
//    element = half (1 cndmask); window h2 index compile-time. K-loop LDS ~= 0.
//  - Block = (btile of 32 batches, d-pair) x 4 colq waves; grid 1024. h self-contained.
//  - Output rows are batches: shfl-reduce across 32 m-lanes, LDS across colq,
//    atomicAdd across the 8 d-pair blocks onto out pre-set to db by CIN_init.
//  - B path/repack unchanged (frag-order d_ws, global->VGPR, dist-2 prefetch).
// Layouts (verified): A: lane A[m=lane&31][k=(lane>>5)*8+t]; B: B[k=(lane>>5)*8+t][n=lane&31];
//  D: D[row=(r&3)+8*(r>>2)+4*(lane>>5)][col=lane&31]  (row = batch, col = m-channel)
// Repacked B (BYTES): ch*8192 + kh*4096 + cg*1024 + lane*16
//  L0 ch=0..29 (IG0/JG0): i=ig*4+kh*2+half, j=jg*8+t; folded upper-tri.
//  L1 ch=30+jg*5+ig: j=jg*4+kh*2+half, i=ig*8+t, zero-pad i>=39.  Total 901,120 B.

typedef _Float16 h2    __attribute__((ext_vector_type(2)));
typedef _Float16 f16x8 __attribute__((ext_vector_type(8)));
typedef __attribute__((ext_vector_type(16))) float f32x16;

#define L0C 30
#define NCH 110

__device__ __constant__ int IG0[L0C] = {0,0,0,0,0, 1,1,1,1,1, 2,2,2,2, 3,3,3,3, 4,4,4, 5,5,5, 6,6, 7,7, 8, 9};
__device__ __constant__ int JG0[L0C] = {0,1,2,3,4, 0,1,2,3,4, 1,2,3,4, 1,2,3,4, 2,3,4, 2,3,4, 3,4, 3,4, 4, 4};
#define IG0T(c) ((c)<5?0:(c)<10?1:(c)<14?2:(c)<18?3:(c)<21?4:(c)<24?5:(c)<26?6:(c)<28?7:(c)<29?8:9)
#define JG0T(c) ((c)<10?((c)%5):(c)<18?(((c)-10)%4+1):(c)<24?(((c)-18)%3+2):(c)<28?(((c)-24)%2+3):4)

// ---------------- weight repack (unchanged from r12) ----------------
__global__ __launch_bounds__(256)
void CIN_repack(const float* __restrict__ f0, const float* __restrict__ f1,
                uint4* __restrict__ ws)
{
    const int tid  = blockIdx.x * 256 + threadIdx.x;   // 56320 total
    const int n    = tid & 127;
    const int slot = tid >> 7;
    const int half = slot & 1;
    const int kh   = (slot >> 1) & 1;
    const int ch   = slot >> 2;                         // 0..109
    float v[8];
    if (ch < L0C) {
        const int ig = IG0[ch], jg = JG0[ch];
        const int i = ig * 4 + kh * 2 + half;
#pragma unroll
        for (int t = 0; t < 8; ++t) {
            const int j = jg * 8 + t;
            float val = 0.f;
            if (i < 39 && j < 39 && j >= i) {
                val = f0[(i * 39 + j) * 128 + n];
                if (j > i) val += f0[(j * 39 + i) * 128 + n];
            }
            v[t] = val;
        }
    } else {
        const int c1 = ch - L0C;
        const int jg = c1 / 5, ig = c1 - jg * 5;
        const int j = jg * 4 + kh * 2 + half;
#pragma unroll
        for (int t = 0; t < 8; ++t) {
            const int i = ig * 8 + t;
            v[t] = (i < 39) ? f1[(i * 64 + j) * 128 + n] : 0.f;
        }
    }
    union { h2 h[4]; uint4 q; } pk;
#pragma unroll
    for (int t = 0; t < 4; ++t)
        pk.h[t] = h2{(_Float16)v[2 * t], (_Float16)v[2 * t + 1]};
    const int lane = half * 32 + (n & 31);
    const int cg   = n >> 5;
    ws[ch * 512 + kh * 256 + cg * 64 + lane] = pk.q;
}

// ---------------- out init: out[b] = db ----------------
__global__ __launch_bounds__(256)
void CIN_init(float* __restrict__ out, const float* __restrict__ db)
{
    const int i = blockIdx.x * 256 + threadIdx.x;
    if (i < 4096) out[i] = db[0];
}

// ---------------- main: grid 1024 = 128 btile x 8 d-pair; 256 thr = 4 colq waves ----
__global__ __launch_bounds__(256)
void CIN_main(const float* __restrict__ x,
              const char* __restrict__ wsB,
              const float* __restrict__ dw,
              float* __restrict__ out)
{
    __shared__ __align__(16) _Float16 xst[32 * 136 + 8]; // [b]: s*64 + i (i<=39), b-stride 136
    __shared__ __align__(4)  _Float16 hst[64 * 66];      // addr = j*66 + row*2 + s
    __shared__ float dws[192];
    __shared__ float redst[4][32];

    const int tid   = threadIdx.x;
    const int wvq   = tid >> 6;        // col-quarter: n in [wvq*32, wvq*32+32)
    const int lane  = tid & 63;
    const int half  = lane >> 5;
    const int b     = lane & 31;       // batch within tile == m-col index
    const int btile = blockIdx.x >> 3;
    const int wd    = blockIdx.x & 7;
    const int d0    = wd * 2;

    const char* wbase = wsB + lane * 16 + wvq * 1024 + 2048;
    f16x8 Bb[2][2];                    // [phase][kh]
    auto loadBg = [&](int ch, f16x8 (&B)[2]) {
        const char* p0 = wbase + (size_t)ch * 8192;
        B[0] = *(const f16x8*)(p0 - 2048);
        B[1] = *(const f16x8*)(p0 + 2048);
    };
    loadBg(0, Bb[0]);
    loadBg(1, Bb[1]);

    // ---- stage x: 32 b x 40 i, float2 (d0,d0+1) each; i=39 zero pad ----
    const float* xb = x + (size_t)btile * 32 * 624 + d0;
    for (int slot = tid; slot < 1280; slot += 256) {
        const int bb = slot / 40, i = slot - bb * 40;
        float2 v = make_float2(0.f, 0.f);
        if (i < 39) v = *(const float2*)(xb + (size_t)bb * 624 + i * 16);
        xst[bb * 136 + i]      = (_Float16)v.x;
        xst[bb * 136 + 64 + i] = (_Float16)v.y;
    }
    if (tid < 192) dws[tid] = dw[tid];
    __syncthreads();

    // ---- xw: lane's batch rows for both d-slices, packed h2 regs (loaded once) ----
    h2 xw[2][20];
#pragma unroll
    for (int s = 0; s < 2; ++s) {
        const _Float16* base = xst + b * 136 + s * 64;
#pragma unroll
        for (int q5 = 0; q5 < 5; ++q5) {
            union { f16x8 v; h2 h[4]; } u;
            u.v = *(const f16x8*)(base + q5 * 8);
#pragma unroll
            for (int q = 0; q < 4; ++q) xw[s][q5 * 4 + q] = u.h[q];
        }
    }

    f32x16 acc[2];
#pragma unroll
    for (int s = 0; s < 2; ++s)
#pragma unroll
        for (int r = 0; r < 16; ++r) acc[s][r] = 0.f;

    h2 sp2[2][2];   // splat operand [s][kh]

    // ---------------- layer 0: 30 folded chunks, fully unrolled ----------------
#pragma unroll
    for (int c = 0; c < L0C; ++c) {
        const int ig = IG0T(c);
        const int jg = JG0T(c);
        if (c == 0 || IG0T(c) != IG0T(c - 1)) {
            // xi: i = ig*4 + kh*2 + half -> reg (ig*2+kh), element = half
#pragma unroll
            for (int s = 0; s < 2; ++s)
#pragma unroll
                for (int kh = 0; kh < 2; ++kh) {
                    const h2 pr = xw[s][ig * 2 + kh];
                    const _Float16 vv = half ? pr.y : pr.x;
                    sp2[s][kh] = h2{vv, vv};
                }
        }
#pragma unroll
        for (int s = 0; s < 2; ++s) {
            union { h2 h[4]; f16x8 v; } a0, a1;
#pragma unroll
            for (int q = 0; q < 4; ++q) {
                a0.h[q] = sp2[s][0] * xw[s][jg * 4 + q];   // v_pk_mul_f16
                a1.h[q] = sp2[s][1] * xw[s][jg * 4 + q];
            }
            acc[s] = __builtin_amdgcn_mfma_f32_32x32x16_f16(a0.v, Bb[c & 1][0], acc[s], 0, 0, 0);
            acc[s] = __builtin_amdgcn_mfma_f32_32x32x16_f16(a1.v, Bb[c & 1][1], acc[s], 0, 0, 0);
        }
        loadBg(c + 2, Bb[c & 1]);      // max 31 < 110; threads into L1 chunks 30/31
    }

    // ---------------- layer-0 epilogue ----------------
    float cs[16];
#pragma unroll
    for (int r = 0; r < 16; ++r) cs[r] = 0.f;
    if (wvq < 2) {
        // m = wvq*32 + b < 64 -> h to LDS, f16, relu'd. row = batch.
#pragma unroll
        for (int s = 0; s < 2; ++s)
#pragma unroll
            for (int r = 0; r < 16; ++r) {
                const int row = (r & 3) + 8 * (r >> 2) + 4 * half;
                hst[(wvq * 32 + b) * 66 + row * 2 + s] =
                    (_Float16)fmaxf(acc[s][r], 0.f);
            }
    } else {
        const float dwv = dws[(wvq - 2) * 32 + b];      // dw[m-64]
#pragma unroll
        for (int s = 0; s < 2; ++s)
#pragma unroll
            for (int r = 0; r < 16; ++r)
                cs[r] += fmaxf(acc[s][r], 0.f) * dwv;
    }
#pragma unroll
    for (int s = 0; s < 2; ++s)
#pragma unroll
        for (int r = 0; r < 16; ++r) acc[s][r] = 0.f;
    __syncthreads();   // h visible

    // ---------------- layer 1: 80 chunks (30..109), 8 outer x 10 unrolled ----------
#pragma unroll 1
    for (int o2 = 0; o2 < 8; ++o2) {
#pragma unroll
        for (int u = 0; u < 10; ++u) {
            const int pos = o2 * 10 + u;           // 0..79, phase = pos&1
            const int ig2 = u % 5;
            if (ig2 == 0) {
                const int jb = (o2 * 2 + u / 5) * 4;
                // splat = h[b, jb+kh*2+half, s] from LDS (4 tiny reads per 5 chunks)
#pragma unroll
                for (int s = 0; s < 2; ++s)
#pragma unroll
                    for (int kh = 0; kh < 2; ++kh) {
                        const _Float16 vv = hst[(jb + kh * 2 + half) * 66 + b * 2 + s];
                        sp2[s][kh] = h2{vv, vv};
                    }
            }
#pragma unroll
            for (int s = 0; s < 2; ++s) {
                union { h2 h[4]; f16x8 v; } a0, a1;
#pragma unroll
                for (int q = 0; q < 4; ++q) {
                    a0.h[q] = sp2[s][0] * xw[s][ig2 * 4 + q];
                    a1.h[q] = sp2[s][1] * xw[s][ig2 * 4 + q];
                }
                acc[s] = __builtin_amdgcn_mfma_f32_32x32x16_f16(a0.v, Bb[pos & 1][0], acc[s], 0, 0, 0);
                acc[s] = __builtin_amdgcn_mfma_f32_32x32x16_f16(a1.v, Bb[pos & 1][1], acc[s], 0, 0, 0);
            }
            int chn = 30 + pos + 2; if (chn > NCH - 1) chn = NCH - 1;
            loadBg(chn, Bb[pos & 1]);
        }
    }

    // ---------------- layer-1 epilogue ----------------
    {
        const float dwv = dws[64 + wvq * 32 + b];
#pragma unroll
        for (int s = 0; s < 2; ++s)
#pragma unroll
            for (int r = 0; r < 16; ++r)
                cs[r] += fmaxf(acc[s][r], 0.f) * dwv;
    }

    // ---- reduce across the 32 m-lanes (rows are batches, same row-set per half) ----
#pragma unroll
    for (int r = 0; r < 16; ++r)
#pragma unroll
        for (int off = 1; off < 32; off <<= 1)
            cs[r] += __shfl_xor(cs[r], off, 64);
    if ((lane & 31) == 0) {
#pragma unroll
        for (int r = 0; r < 16; ++r) {
            const int row = (r & 3) + 8 * (r >> 2) + 4 * half;
            redst[wvq][row] = cs[r];
        }
    }
    __syncthreads();
    if (tid < 32) {
        const float v = redst[0][tid] + redst[1][tid] + redst[2][tid] + redst[3][tid];
        atomicAdd(&out[btile * 32 + tid], v);   // 8 d-pair blocks accumulate
    }
}

extern "C" void kernel_launch(void* const* d_in, const int* in_sizes, int n_in,
                              void* d_out, int out_size, void* d_ws, size_t ws_size,
                              hipStream_t stream)
{
    const float* x  = (const float*)d_in[0];
    const float* f0 = (const float*)d_in[1];
    const float* f1 = (const float*)d_in[2];
    const float* dw = (const float*)d_in[3];
    const float* db = (const float*)d_in[4];
    float* out = (float*)d_out;

    CIN_repack<<<dim3(220), dim3(256), 0, stream>>>(f0, f1, (uint4*)d_ws);
    CIN_init<<<dim3(16), dim3(256), 0, stream>>>(out, db);
    CIN_main<<<dim3(1024), dim3(256), 0, stream>>>(x, (const char*)d_ws, dw, out);
}

// Round 14
// 123.850 us; speedup vs baseline: 1.0893x; 1.0893x over previous
//
#include <hip/hip_runtime.h>

// B=4096, F0=39, D=16, L=(128,128), H1=64
// Round-14: r11 register-resident structure with (a) launch_bounds(256,2) so the
// allocator actually grants the ~125-VGPR live set (r4-r8 precedent; waves_per_eu
// was ignored in r11), and (b) B prefetch distance 4 (Bb[4][2], 8 loads in
// flight/wave) to cover contended-L2 latency with per-wave ILP — the one lever
// the r6-r13 elimination table leaves (TLP/VALU/LDS/L2-bytes all proven non-binding).
//  - mfma_f32_32x32x16_f16, M=32 = 2 batches x 16 d, N=128, K=(i,j) folded:
//    L0 upper-tri 30 chunks + L1 80 = 110.  Wave = 2 M-tiles x col-quarter.
//  - xw[2][20] h2 regs hold x[0..39] per lane: A-frags reg-only in L0; L1 splats
//    from hsH every 5 chunks.  K-loop has no barriers.
// Layouts (verified): A: lane A[m=lane&31][k=(lane>>5)*8+t]; B: B[k=(lane>>5)*8+t][n=lane&31];
//  D: D[row=(r&3)+8*(r>>2)+4*(lane>>5)][col=lane&31]
// Repacked B (BYTES): ch*8192 + kh*4096 + cg*1024 + lane*16
//  L0 ch=0..29 (IG0/JG0): i=ig*4+kh*2+half, j=jg*8+t; folded (W'[i,j]=W[i,j]+W[j,i], j>i).
//  L1 ch=30+jg*5+ig: j=jg*4+kh*2+half, i=ig*8+t, zero-pad i>=39.  Total 901,120 B.

typedef _Float16 h2    __attribute__((ext_vector_type(2)));
typedef _Float16 f16x8 __attribute__((ext_vector_type(8)));
typedef __attribute__((ext_vector_type(16))) float f32x16;

#define XBB 1160   // per-batch halfs in xsH: 16 rows * 72 + 8 skew (2320 B, 16-aligned)
#define L0C 30
#define NCH 110

__device__ __constant__ int IG0[L0C] = {0,0,0,0,0, 1,1,1,1,1, 2,2,2,2, 3,3,3,3, 4,4,4, 5,5,5, 6,6, 7,7, 8, 9};
__device__ __constant__ int JG0[L0C] = {0,1,2,3,4, 0,1,2,3,4, 1,2,3,4, 1,2,3,4, 2,3,4, 2,3,4, 3,4, 3,4, 4, 4};
#define IG0T(c) ((c)<5?0:(c)<10?1:(c)<14?2:(c)<18?3:(c)<21?4:(c)<24?5:(c)<26?6:(c)<28?7:(c)<29?8:9)
#define JG0T(c) ((c)<10?((c)%5):(c)<18?(((c)-10)%4+1):(c)<24?(((c)-18)%3+2):(c)<28?(((c)-24)%2+3):4)

// ---------------- weight repack (unchanged layout) ----------------
__global__ __launch_bounds__(256)
void CIN_repack(const float* __restrict__ f0, const float* __restrict__ f1,
                uint4* __restrict__ ws)
{
    const int tid  = blockIdx.x * 256 + threadIdx.x;   // 56320 total
    const int n    = tid & 127;
    const int slot = tid >> 7;
    const int half = slot & 1;
    const int kh   = (slot >> 1) & 1;
    const int ch   = slot >> 2;                         // 0..109
    float v[8];
    if (ch < L0C) {
        const int ig = IG0[ch], jg = JG0[ch];
        const int i = ig * 4 + kh * 2 + half;
#pragma unroll
        for (int t = 0; t < 8; ++t) {
            const int j = jg * 8 + t;
            float val = 0.f;
            if (i < 39 && j < 39 && j >= i) {
                val = f0[(i * 39 + j) * 128 + n];
                if (j > i) val += f0[(j * 39 + i) * 128 + n];
            }
            v[t] = val;
        }
    } else {
        const int c1 = ch - L0C;
        const int jg = c1 / 5, ig = c1 - jg * 5;
        const int j = jg * 4 + kh * 2 + half;
#pragma unroll
        for (int t = 0; t < 8; ++t) {
            const int i = ig * 8 + t;
            v[t] = (i < 39) ? f1[(i * 64 + j) * 128 + n] : 0.f;
        }
    }
    union { h2 h[4]; uint4 q; } pk;
#pragma unroll
    for (int t = 0; t < 4; ++t)
        pk.h[t] = h2{(_Float16)v[2 * t], (_Float16)v[2 * t + 1]};
    const int lane = half * 32 + (n & 31);
    const int cg   = n >> 5;
    ws[ch * 512 + kh * 256 + cg * 64 + lane] = pk.q;
}

// ---------------- main: grid 1024, 4 batches/block, 4 waves, dist-4 prefetch ----
__global__ __launch_bounds__(256, 2)
void CIN_main(const float* __restrict__ x,
              const char* __restrict__ wsB,
              const float* __restrict__ dw,
              const float* __restrict__ db,
              float* __restrict__ out)
{
    __shared__ __align__(16) _Float16 xsH[4 * XBB];    // [bb]: 16 rows of 72 (i<=39 used)
    __shared__ __align__(4)  _Float16 hsH[4][64][18];  // [bb][j][d]
    __shared__ float dws[192];
    __shared__ float red[4][4];

    const int tid  = threadIdx.x;
    const int w    = tid >> 6;     // col-quarter: n in [w*32, w*32+32)
    const int lane = tid & 63;
    const int half = lane >> 5;
    const int d    = lane & 15;
    const int bsel = (lane >> 4) & 1;
    const int col  = lane & 31;

    // B frag base; rebase +2048 so kh offsets {-2048,+2048} fit imm13
    const char* wbase = wsB + lane * 16 + w * 1024 + 2048;
    f16x8 Bb[4][2];                // [phase = ch&3][kh]
    auto loadBg = [&](int ch, f16x8 (&B)[2]) {
        const char* p0 = wbase + (size_t)ch * 8192;
        B[0] = *(const f16x8*)(p0 - 2048);
        B[1] = *(const f16x8*)(p0 + 2048);
    };

    loadBg(0, Bb[0]);              // distance-4 pipeline primed before x staging
    loadBg(1, Bb[1]);
    loadBg(2, Bb[2]);
    loadBg(3, Bb[3]);

    // ---- stage x for 4 batches as f16 (624 float4, coalesced) ----
    const float4* xg4 = (const float4*)(x + (size_t)blockIdx.x * 4 * 624);
    for (int e4 = tid; e4 < 624; e4 += 256) {
        float4 v = xg4[e4];
        int bb = e4 / 156, r = e4 - bb * 156;
        int i = r >> 2, d0 = (r & 3) * 4;
        _Float16* bp = xsH + bb * XBB + i;
        bp[(d0 + 0) * 72] = (_Float16)v.x; bp[(d0 + 1) * 72] = (_Float16)v.y;
        bp[(d0 + 2) * 72] = (_Float16)v.z; bp[(d0 + 3) * 72] = (_Float16)v.w;
    }
    if (tid < 64) { int bb = tid >> 4, dd = tid & 15; xsH[bb * XBB + dd * 72 + 39] = (_Float16)0.f; }
    if (tid < 192) dws[tid] = dw[tid];
    __syncthreads();

    const _Float16* xrow[2] = {
        xsH + (0 * 2 + bsel) * XBB + d * 72,
        xsH + (1 * 2 + bsel) * XBB + d * 72
    };

    // ---- xw: the 40 halfs of x[0..39] per lane-batch, REGISTERS, serve both layers ----
    h2 xw[2][20];
#pragma unroll
    for (int p = 0; p < 2; ++p)
#pragma unroll
        for (int w5 = 0; w5 < 5; ++w5) {
            union { f16x8 v; h2 h[4]; } u;
            u.v = *(const f16x8*)(xrow[p] + w5 * 8);    // one ds_read_b128
#pragma unroll
            for (int q = 0; q < 4; ++q) xw[p][w5 * 4 + q] = u.h[q];
        }

    f32x16 acc[2];
#pragma unroll
    for (int p = 0; p < 2; ++p)
#pragma unroll
        for (int r = 0; r < 16; ++r) acc[p][r] = 0.f;

    h2 sp2[2][2];

    // ---------------- layer 0: 30 folded chunks, fully unrolled, phase = c&3 ------
#pragma unroll
    for (int c = 0; c < L0C; ++c) {
        const int ig = IG0T(c);
        const int jg = JG0T(c);
        if ((c == 0) || (IG0T(c) != IG0T(c - 1))) {
            // xi: i = ig*4 + kh*2 + half -> reg xw[p][ig*2+kh], element = half
#pragma unroll
            for (int p = 0; p < 2; ++p)
#pragma unroll
                for (int kh = 0; kh < 2; ++kh) {
                    const h2 pr = xw[p][ig * 2 + kh];
                    const _Float16 vv = half ? pr.y : pr.x;
                    sp2[p][kh] = h2{vv, vv};
                }
        }
#pragma unroll
        for (int p = 0; p < 2; ++p) {
            union { h2 h[4]; f16x8 v; } a0, a1;
#pragma unroll
            for (int q = 0; q < 4; ++q) {
                a0.h[q] = sp2[p][0] * xw[p][jg * 4 + q];   // v_pk_mul_f16
                a1.h[q] = sp2[p][1] * xw[p][jg * 4 + q];
            }
            acc[p] = __builtin_amdgcn_mfma_f32_32x32x16_f16(a0.v, Bb[c & 3][0], acc[p], 0, 0, 0);
            acc[p] = __builtin_amdgcn_mfma_f32_32x32x16_f16(a1.v, Bb[c & 3][1], acc[p], 0, 0, 0);
        }
        loadBg(c + 4, Bb[c & 3]);   // max 33 < 110; threads into L1 chunks 30..33
    }

    // ---------------- layer-0 epilogue ----------------
    float cs[4] = {0.f, 0.f, 0.f, 0.f};
    if (w < 2) {
#pragma unroll
        for (int p = 0; p < 2; ++p)
#pragma unroll
            for (int r = 0; r < 16; r += 2) {
                const int row = (r & 3) + 8 * (r >> 2) + 4 * half;
                h2 pr = h2{(_Float16)fmaxf(acc[p][r],     0.f),
                           (_Float16)fmaxf(acc[p][r + 1], 0.f)};
                *(h2*)&hsH[p * 2 + (row >> 4)][w * 32 + col][row & 15] = pr;
            }
    } else {
        const float dwv = dws[(w - 2) * 32 + col];      // dw[n-64]
#pragma unroll
        for (int p = 0; p < 2; ++p)
#pragma unroll
            for (int r = 0; r < 16; ++r) {
                const int row = (r & 3) + 8 * (r >> 2) + 4 * half;
                cs[p * 2 + (row >> 4)] += fmaxf(acc[p][r], 0.f) * dwv;
            }
    }
#pragma unroll
    for (int p = 0; p < 2; ++p)
#pragma unroll
        for (int r = 0; r < 16; ++r) acc[p][r] = 0.f;
    __syncthreads();   // h visible to all waves

    // -------- layer 1: 4 outer x 20 unrolled chunks (30..109), phase=(2+u)&3 ------
#pragma unroll 1
    for (int o2 = 0; o2 < 4; ++o2) {
#pragma unroll
        for (int u = 0; u < 20; ++u) {
            const int ig2 = u % 5;                 // window index, compile-time
            if (ig2 == 0) {
                const int jb = (o2 * 4 + u / 5) * 4;
#pragma unroll
                for (int p = 0; p < 2; ++p)
#pragma unroll
                    for (int kh = 0; kh < 2; ++kh) {
                        const _Float16 s = hsH[p * 2 + bsel][jb + kh * 2 + half][d];
                        sp2[p][kh] = h2{s, s};
                    }
            }
#pragma unroll
            for (int p = 0; p < 2; ++p) {
                union { h2 h[4]; f16x8 v; } a0, a1;
#pragma unroll
                for (int q = 0; q < 4; ++q) {
                    a0.h[q] = sp2[p][0] * xw[p][ig2 * 4 + q];
                    a1.h[q] = sp2[p][1] * xw[p][ig2 * 4 + q];
                }
                acc[p] = __builtin_amdgcn_mfma_f32_32x32x16_f16(a0.v, Bb[(2 + u) & 3][0], acc[p], 0, 0, 0);
                acc[p] = __builtin_amdgcn_mfma_f32_32x32x16_f16(a1.v, Bb[(2 + u) & 3][1], acc[p], 0, 0, 0);
            }
            int chn = 30 + o2 * 20 + u + 4; if (chn > NCH - 1) chn = NCH - 1;
            loadBg(chn, Bb[(2 + u) & 3]);
        }
    }

    // ---------------- layer-1 epilogue + reduction ----------------
    {
        const float dwv = dws[64 + w * 32 + col];
#pragma unroll
        for (int p = 0; p < 2; ++p)
#pragma unroll
            for (int r = 0; r < 16; ++r) {
                const int row = (r & 3) + 8 * (r >> 2) + 4 * half;
                cs[p * 2 + (row >> 4)] += fmaxf(acc[p][r], 0.f) * dwv;
            }
    }
#pragma unroll
    for (int rr = 0; rr < 4; ++rr)
#pragma unroll
        for (int off = 32; off > 0; off >>= 1)
            cs[rr] += __shfl_xor(cs[rr], off, 64);
    if (lane == 0) {
#pragma unroll
        for (int rr = 0; rr < 4; ++rr) red[w][rr] = cs[rr];
    }
    __syncthreads();
    if (tid < 4)
        out[blockIdx.x * 4 + tid] = red[0][tid] + red[1][tid] + red[2][tid] + red[3][tid] + db[0];
}

extern "C" void kernel_launch(void* const* d_in, const int* in_sizes, int n_in,
                              void* d_out, int out_size, void* d_ws, size_t ws_size,
                              hipStream_t stream)
{
    const float* x  = (const float*)d_in[0];
    const float* f0 = (const float*)d_in[1];
    const float* f1 = (const float*)d_in[2];
    const float* dw = (const float*)d_in[3];
    const float* db = (const float*)d_in[4];
    float* out = (float*)d_out;

    CIN_repack<<<dim3(220), dim3(256), 0, stream>>>(f0, f1, (uint4*)d_ws);
    CIN_main<<<dim3(1024), dim3(256), 0, stream>>>(x, (const char*)d_ws, dw, db, out);
}